// Round 8
// baseline (3584.708 us; speedup 1.0000x reference)
//
#include <hip/hip_runtime.h>
#include <hip/hip_bf16.h>
#include <cstdio>

// QuantGRU: T=512, B=64, I=H=1024.
// k_gemm_x precomputes all x-projections (parallel GEMM, bf16 MFMA).
// k_recurrent: persistent 128-WG kernel. Each WG owns a 16-col W-slice
// (pinned in VGPRs) and serves TWO independent 16-row batch teams,
// phase-staggered so the mall round-trip of team A's tagged h-exchange
// hides under team B's compute (and vice versa). h exchange = r6-proven
// tagged words: u32 = (bf16(h)<<16)|step, sc0 sc1 both sides, no flags,
// no fences. Poll caps prevent timeouts.

typedef short bf16x8 __attribute__((ext_vector_type(8)));
typedef float f32x4 __attribute__((ext_vector_type(4)));
typedef int i32x4 __attribute__((ext_vector_type(4)));

#define NT 512
#define NB 64
#define NH 1024
#define NBH 65536   // NB*NH

// ws layout (bytes)
#define OFF_HBUF  4096UL                                   // 2 x 64x1024 u32 = 512KB (tagged)
#define OFF_WCAT  (OFF_HBUF + 2UL * NB * NH * 4)           // 3072x1024 bf16 (Wri|Wii|Wni)
#define OFF_WH    (OFF_WCAT + 3UL * NH * NH * 2)           // 3 x 1024x1024 bf16 (Wrh,Wih,Wnh)
#define OFF_GR    (OFF_WH   + 3UL * NH * NH * 2)           // 32768x1024 bf16
#define OFF_GI    (OFF_GR   + (unsigned long)NT * NB * NH * 2)
#define WS_NEED   (OFF_GI   + (unsigned long)NT * NB * NH * 2)   // ~140.6 MB

__device__ __forceinline__ float clampf(float x) { return fminf(fmaxf(x, -1.f), 1.f); }

__device__ __forceinline__ unsigned short f2bf(float x) {
  __hip_bfloat16 h = __float2bfloat16(x);
  union { __hip_bfloat16 h; unsigned short u; } cv;
  cv.h = h;
  return cv.u;
}
__device__ __forceinline__ float bf2f(unsigned short u) {
  return __uint_as_float(((unsigned)u) << 16);
}
__device__ __forceinline__ float frcp(float x) { return __builtin_amdgcn_rcpf(x); }
__device__ __forceinline__ float fsigmoid(float x) { return frcp(1.f + __expf(-x)); }
__device__ __forceinline__ float ftanh(float z) { return 1.f - 2.f * frcp(1.f + __expf(2.f * z)); }

// 8x dwordx4 cached loads into asm-pinned regs (no remat possible).
__device__ __forceinline__ void load_frags8(const unsigned short* p, i32x4 a[8]) {
  asm volatile(
      "global_load_dwordx4 %0, %8, off\n\t"
      "global_load_dwordx4 %1, %8, off offset:64\n\t"
      "global_load_dwordx4 %2, %8, off offset:128\n\t"
      "global_load_dwordx4 %3, %8, off offset:192\n\t"
      "global_load_dwordx4 %4, %8, off offset:256\n\t"
      "global_load_dwordx4 %5, %8, off offset:320\n\t"
      "global_load_dwordx4 %6, %8, off offset:384\n\t"
      "global_load_dwordx4 %7, %8, off offset:448\n\t"
      "s_waitcnt vmcnt(0)"
      : "=&v"(a[0]), "=&v"(a[1]), "=&v"(a[2]), "=&v"(a[3]),
        "=&v"(a[4]), "=&v"(a[5]), "=&v"(a[6]), "=&v"(a[7])
      : "v"(p)
      : "memory");
}
// 16x dwordx4 tagged-word loads, straight from the mall (r6-proven sc0 sc1).
__device__ __forceinline__ void load_h_tagged(const unsigned int* p, i32x4 a[16]) {
  asm volatile(
      "global_load_dwordx4 %0, %16, off sc0 sc1\n\t"
      "global_load_dwordx4 %1, %16, off offset:16 sc0 sc1\n\t"
      "global_load_dwordx4 %2, %16, off offset:128 sc0 sc1\n\t"
      "global_load_dwordx4 %3, %16, off offset:144 sc0 sc1\n\t"
      "global_load_dwordx4 %4, %16, off offset:256 sc0 sc1\n\t"
      "global_load_dwordx4 %5, %16, off offset:272 sc0 sc1\n\t"
      "global_load_dwordx4 %6, %16, off offset:384 sc0 sc1\n\t"
      "global_load_dwordx4 %7, %16, off offset:400 sc0 sc1\n\t"
      "global_load_dwordx4 %8, %16, off offset:512 sc0 sc1\n\t"
      "global_load_dwordx4 %9, %16, off offset:528 sc0 sc1\n\t"
      "global_load_dwordx4 %10, %16, off offset:640 sc0 sc1\n\t"
      "global_load_dwordx4 %11, %16, off offset:656 sc0 sc1\n\t"
      "global_load_dwordx4 %12, %16, off offset:768 sc0 sc1\n\t"
      "global_load_dwordx4 %13, %16, off offset:784 sc0 sc1\n\t"
      "global_load_dwordx4 %14, %16, off offset:896 sc0 sc1\n\t"
      "global_load_dwordx4 %15, %16, off offset:912 sc0 sc1\n\t"
      "s_waitcnt vmcnt(0)"
      : "=&v"(a[0]), "=&v"(a[1]), "=&v"(a[2]), "=&v"(a[3]),
        "=&v"(a[4]), "=&v"(a[5]), "=&v"(a[6]), "=&v"(a[7]),
        "=&v"(a[8]), "=&v"(a[9]), "=&v"(a[10]), "=&v"(a[11]),
        "=&v"(a[12]), "=&v"(a[13]), "=&v"(a[14]), "=&v"(a[15])
      : "v"(p)
      : "memory");
}
// fire-and-forget write-through store (r3/r6-proven visibility path)
__device__ __forceinline__ void store_u32_wt(unsigned int* p, unsigned v) {
  asm volatile("global_store_dword %0, %1, off sc0 sc1" :: "v"(p), "v"(v) : "memory");
}

// poll the 64 tagged words this wave's MFMA needs until all tags >= tgt,
// then unpack hi16 halves into bf16x8 fragments. Capped.
__device__ __forceinline__ void poll_load_frag(const unsigned int* hp, unsigned tgt, i32x4 afi[8]) {
  i32x4 raw[16];
  for (unsigned it = 0;; ++it) {
    load_h_tagged(hp, raw);
    unsigned mn = 0xFFFFFFFFu;
#pragma unroll
    for (int q = 0; q < 16; ++q)
#pragma unroll
      for (int e = 0; e < 4; ++e)
        mn = min(mn, ((unsigned)raw[q][e]) & 0xFFFFu);
    if (__all((int)(mn >= tgt)) || it > (1u << 14)) break;
    __builtin_amdgcn_s_sleep(2);
  }
#pragma unroll
  for (int s = 0; s < 8; ++s) {
    i32x4 q;
    q[0] = (int)__builtin_amdgcn_perm((unsigned)raw[2 * s][1], (unsigned)raw[2 * s][0], 0x07060302u);
    q[1] = (int)__builtin_amdgcn_perm((unsigned)raw[2 * s][3], (unsigned)raw[2 * s][2], 0x07060302u);
    q[2] = (int)__builtin_amdgcn_perm((unsigned)raw[2 * s + 1][1], (unsigned)raw[2 * s + 1][0], 0x07060302u);
    q[3] = (int)__builtin_amdgcn_perm((unsigned)raw[2 * s + 1][3], (unsigned)raw[2 * s + 1][2], 0x07060302u);
    afi[s] = q;
  }
}

// ---------------- kernel 0: weights f32 -> bf16 ---------------------------
__global__ void k_convert_weights(const float* __restrict__ wri, const float* __restrict__ wii,
                                  const float* __restrict__ wni, const float* __restrict__ wrh,
                                  const float* __restrict__ wih, const float* __restrict__ wnh,
                                  unsigned short* __restrict__ wcat, unsigned short* __restrict__ wh) {
  const long total = 6L * 1024 * 1024;
  long stride = (long)gridDim.x * blockDim.x * 4;
  for (long i = ((long)blockIdx.x * blockDim.x + threadIdx.x) * 4; i < total; i += stride) {
    int m = (int)(i >> 20);              // which matrix
    long off = i & 1048575L;
    const float* srcs[6] = {wri, wii, wni, wrh, wih, wnh};
    float4 v = *(const float4*)(srcs[m] + off);
    ushort4 o;
    o.x = f2bf(v.x); o.y = f2bf(v.y); o.z = f2bf(v.z); o.w = f2bf(v.w);
    unsigned short* dst = (m < 3) ? (wcat + ((long)m << 20) + off)
                                  : (wh + ((long)(m - 3) << 20) + off);
    *(ushort4*)dst = o;
  }
}

// ---------------- kernel 1: input projections GEMM ------------------------
#define BK 64
__launch_bounds__(256)
__global__ void k_gemm_x(const float* __restrict__ A,              // X f32 [32768][1024]
                         const unsigned short* __restrict__ Bw,    // Wcat bf16 [3072][1024]
                         unsigned short* __restrict__ gr, unsigned short* __restrict__ gi,
                         float* __restrict__ gni,                  // = d_out plane [32768][1024]
                         const float* __restrict__ br, const float* __restrict__ bi,
                         const float* __restrict__ bni) {
  __shared__ unsigned short As[128 * BK];
  __shared__ unsigned short Bs[128 * BK];

  int bid = blockIdx.x;
  int bm = bid / 24, bn = bid % 24;
  int tid = threadIdx.x;
  int lane = tid & 63, w = tid >> 6;
  int wm = w >> 1, wn = w & 1;

  long arow0 = (long)bm * 128;
  long brow0 = (long)bn * 128;

  f32x4 acc[4][4] = {};

  for (int kt = 0; kt < 1024; kt += BK) {
    __syncthreads();
#pragma unroll
    for (int it = 0; it < 4; ++it) {
      int f = it * 2048 + tid * 8;
      int r = f >> 6, c = f & 63;
      const float* ap = A + (arow0 + r) * 1024 + kt + c;
      float4 v0 = *(const float4*)ap;
      float4 v1 = *(const float4*)(ap + 4);
      int4 p;
      p.x = (int)(f2bf(clampf(v0.x)) | ((unsigned)f2bf(clampf(v0.y)) << 16));
      p.y = (int)(f2bf(clampf(v0.z)) | ((unsigned)f2bf(clampf(v0.w)) << 16));
      p.z = (int)(f2bf(clampf(v1.x)) | ((unsigned)f2bf(clampf(v1.y)) << 16));
      p.w = (int)(f2bf(clampf(v1.z)) | ((unsigned)f2bf(clampf(v1.w)) << 16));
      *(int4*)(&As[f]) = p;
      *(int4*)(&Bs[f]) = *(const int4*)(Bw + (brow0 + r) * 1024 + kt + c);
    }
    __syncthreads();
#pragma unroll
    for (int ks = 0; ks < 2; ++ks) {
      bf16x8 a[4], b[4];
#pragma unroll
      for (int fm = 0; fm < 4; ++fm)
        a[fm] = *(const bf16x8*)(&As[(wm * 64 + fm * 16 + (lane & 15)) * BK + ks * 32 + (lane >> 4) * 8]);
#pragma unroll
      for (int fn = 0; fn < 4; ++fn)
        b[fn] = *(const bf16x8*)(&Bs[(wn * 64 + fn * 16 + (lane & 15)) * BK + ks * 32 + (lane >> 4) * 8]);
#pragma unroll
      for (int fm = 0; fm < 4; ++fm)
#pragma unroll
        for (int fn = 0; fn < 4; ++fn)
          acc[fm][fn] = __builtin_amdgcn_mfma_f32_16x16x32_bf16(a[fm], b[fn], acc[fm][fn], 0, 0, 0);
    }
  }

  int g = bn >> 3;  // 0:r 1:i 2:ni (uniform per block)
  const float* bias = (g == 0) ? br : (g == 1) ? bi : bni;
#pragma unroll
  for (int fm = 0; fm < 4; ++fm) {
    long m = arow0 + wm * 64 + fm * 16 + (lane >> 4) * 4;
#pragma unroll
    for (int fn = 0; fn < 4; ++fn) {
      long n = brow0 + wn * 64 + fn * 16 + (lane & 15);
      long colg = n & 1023;
      float bv = bias[colg];
#pragma unroll
      for (int r2 = 0; r2 < 4; ++r2) {
        float v = acc[fm][fn][r2] + bv;
        long idx = (m + r2) * 1024 + colg;
        if (g == 0)      gr[idx] = f2bf(v);
        else if (g == 1) gi[idx] = f2bf(v);
        else             gni[idx] = clampf(v);   // pre-clamped ni (includes bias)
      }
    }
  }
}

// ---------------- kernel 2: persistent recurrence (two-team pipeline) -----
// 128 WGs x 256 threads. WG = (j = wg&63: hidden cols j*16..+16, q = wg>>6).
// Teams A/B = batch-row groups mbA=2q, mbB=2q+1 (16 rows each), independent
// recurrences sharing this WG's W-slice (pinned 96 VGPRs). Waves K-split 256.
// Phase order staggers each team's mall RT under the other team's compute.
__launch_bounds__(256, 1)
__global__ void k_recurrent(const unsigned short* __restrict__ wh,   // [3][1024][1024] bf16
                            const unsigned short* __restrict__ gr,
                            const unsigned short* __restrict__ gi,
                            const float* __restrict__ state,
                            const float* __restrict__ bias_nh,
                            unsigned int* __restrict__ hbuf,         // [2][64][1024] u32 tagged
                            float* __restrict__ out) {               // [512][64][1024] + [64][1024]
  __shared__ float redA[4][3][256];
  __shared__ float redB[4][3][256];

  int tid = threadIdx.x;
  int lane = tid & 63, w = tid >> 6;
  int wg = blockIdx.x;
  int q = wg >> 6;        // 0..1
  int j = wg & 63;        // 16-col slot
  int mbA = 2 * q, mbB = 2 * q + 1;

  // ---- pinned weight fragments (96 VGPRs, 3 gates x 8 k-frags) ----
  int frow = j * 16 + (lane & 15);
  int fk0 = w * 256 + ((lane >> 4) * 8);
  i32x4 wfi[3][8];
#pragma unroll
  for (int g = 0; g < 3; ++g)
    load_frags8(wh + ((long)g << 20) + (long)frow * 1024 + fk0, wfi[g]);

  // ---- per-thread pointwise cells (one per team) ----
  int crow = tid >> 4, ccol = tid & 15;
  int colg = j * 16 + ccol;
  long cellA = (long)(mbA * 16 + crow) * 1024 + colg;
  long cellB = (long)(mbB * 16 + crow) * 1024 + colg;
  float hA = clampf(state[cellA]);
  float hB = clampf(state[cellB]);
  float bnh = bias_nh[colg];

  // ---- A-fragment addressing ----
  long aofsA = (long)(mbA * 16 + (lane & 15)) * 1024 + fk0;
  long aofsB = (long)(mbB * 16 + (lane & 15)) * 1024 + fk0;

  // ---- t=0 fragments straight from clamp(state) ----
  i32x4 afiA[8], afiB[8];
#pragma unroll
  for (int s = 0; s < 8; ++s) {
    const float* spA = state + aofsA + s * 32;
    const float* spB = state + aofsB + s * 32;
    float4 a0 = *(const float4*)spA, a1 = *(const float4*)(spA + 4);
    float4 b0 = *(const float4*)spB, b1 = *(const float4*)(spB + 4);
    i32x4 qa, qb;
    qa[0] = (int)(f2bf(clampf(a0.x)) | ((unsigned)f2bf(clampf(a0.y)) << 16));
    qa[1] = (int)(f2bf(clampf(a0.z)) | ((unsigned)f2bf(clampf(a0.w)) << 16));
    qa[2] = (int)(f2bf(clampf(a1.x)) | ((unsigned)f2bf(clampf(a1.y)) << 16));
    qa[3] = (int)(f2bf(clampf(a1.z)) | ((unsigned)f2bf(clampf(a1.w)) << 16));
    qb[0] = (int)(f2bf(clampf(b0.x)) | ((unsigned)f2bf(clampf(b0.y)) << 16));
    qb[1] = (int)(f2bf(clampf(b0.z)) | ((unsigned)f2bf(clampf(b0.w)) << 16));
    qb[2] = (int)(f2bf(clampf(b1.x)) | ((unsigned)f2bf(clampf(b1.y)) << 16));
    qb[3] = (int)(f2bf(clampf(b1.z)) | ((unsigned)f2bf(clampf(b1.w)) << 16));
    afiA[s] = qa; afiB[s] = qb;
  }

  // prefetch t=0 pointwise inputs
  float grvA = bf2f(gr[cellA]), givA = bf2f(gi[cellA]), gnivA = out[cellA];
  float grvB = bf2f(gr[cellB]), givB = bf2f(gi[cellB]), gnivB = out[cellB];

#pragma unroll 1
  for (int t = 0; t < NT; ++t) {
    unsigned tgt = (unsigned)(t + 1);
    long bank = (long)(tgt & 1) * NBH;

    // ======== phase A ========
    {
      f32x4 acc[3] = {};
#pragma unroll
      for (int s = 0; s < 8; ++s) {
        bf16x8 a = __builtin_bit_cast(bf16x8, afiA[s]);
#pragma unroll
        for (int g = 0; g < 3; ++g)
          acc[g] = __builtin_amdgcn_mfma_f32_16x16x32_bf16(
              a, __builtin_bit_cast(bf16x8, wfi[g][s]), acc[g], 0, 0, 0);
      }
#pragma unroll
      for (int g = 0; g < 3; ++g)
#pragma unroll
        for (int r = 0; r < 4; ++r)
          redA[w][g][((lane >> 4) * 4 + r) * 16 + (lane & 15)] = acc[g][r];
    }
    __syncthreads();
    {
      float pr = redA[0][0][tid] + redA[1][0][tid] + redA[2][0][tid] + redA[3][0][tid];
      float pi = redA[0][1][tid] + redA[1][1][tid] + redA[2][1][tid] + redA[3][1][tid];
      float pn = redA[0][2][tid] + redA[1][2][tid] + redA[2][2][tid] + redA[3][2][tid];
      float rg = fsigmoid(pr + grvA);
      float ig = fsigmoid(pi + givA);
      float ng = ftanh(gnivA + clampf(rg * (pn + bnh)));
      float sx = clampf(hA) - ng;
      float hy = ng + clampf(ig * sx);
      out[(long)t * NBH + cellA] = hy;
      hA = hy;
      store_u32_wt(hbuf + bank + cellA, ((unsigned)f2bf(hy) << 16) | tgt);
      if (t + 1 < NT) {
        long g2 = (long)tgt * NBH + cellA;
        grvA = bf2f(gr[g2]); givA = bf2f(gi[g2]); gnivA = out[g2];
      }
    }

    // ======== phase B ========
    {
      f32x4 acc[3] = {};
#pragma unroll
      for (int s = 0; s < 8; ++s) {
        bf16x8 a = __builtin_bit_cast(bf16x8, afiB[s]);
#pragma unroll
        for (int g = 0; g < 3; ++g)
          acc[g] = __builtin_amdgcn_mfma_f32_16x16x32_bf16(
              a, __builtin_bit_cast(bf16x8, wfi[g][s]), acc[g], 0, 0, 0);
      }
#pragma unroll
      for (int g = 0; g < 3; ++g)
#pragma unroll
        for (int r = 0; r < 4; ++r)
          redB[w][g][((lane >> 4) * 4 + r) * 16 + (lane & 15)] = acc[g][r];
    }
    __syncthreads();
    {
      float pr = redB[0][0][tid] + redB[1][0][tid] + redB[2][0][tid] + redB[3][0][tid];
      float pi = redB[0][1][tid] + redB[1][1][tid] + redB[2][1][tid] + redB[3][1][tid];
      float pn = redB[0][2][tid] + redB[1][2][tid] + redB[2][2][tid] + redB[3][2][tid];
      float rg = fsigmoid(pr + grvB);
      float ig = fsigmoid(pi + givB);
      float ng = ftanh(gnivB + clampf(rg * (pn + bnh)));
      float sx = clampf(hB) - ng;
      float hy = ng + clampf(ig * sx);
      out[(long)t * NBH + cellB] = hy;
      hB = hy;
      store_u32_wt(hbuf + bank + cellB, ((unsigned)f2bf(hy) << 16) | tgt);
      if (t + 1 < NT) {
        long g2 = (long)tgt * NBH + cellB;
        grvB = bf2f(gr[g2]); givB = bf2f(gi[g2]); gnivB = out[g2];
      }
    }

    // ======== exchange: A first (stored a phase ago), then B ========
    if (t + 1 < NT) {
      poll_load_frag(hbuf + bank + aofsA, tgt, afiA);
      poll_load_frag(hbuf + bank + aofsB, tgt, afiB);
    }
  }

  // last hidden states
  out[(long)NT * NBH + cellA] = hA;
  out[(long)NT * NBH + cellB] = hB;
}

// ---------------------------------------------------------------------------
extern "C" void kernel_launch(void* const* d_in, const int* in_sizes, int n_in,
                              void* d_out, int out_size, void* d_ws, size_t ws_size,
                              hipStream_t stream) {
  const float* inputs = (const float*)d_in[0];
  const float* state  = (const float*)d_in[1];
  const float* wri = (const float*)d_in[2];
  const float* wii = (const float*)d_in[3];
  const float* wni = (const float*)d_in[4];
  const float* wrh = (const float*)d_in[5];
  const float* wih = (const float*)d_in[6];
  const float* wnh = (const float*)d_in[7];
  const float* br  = (const float*)d_in[8];
  const float* bi  = (const float*)d_in[9];
  const float* bni = (const float*)d_in[10];
  const float* bnh = (const float*)d_in[11];

  if (ws_size < WS_NEED) {
    fprintf(stderr, "kernel_launch: ws too small (%zu < %lu)\n", ws_size, WS_NEED);
    return;
  }

  char* ws = (char*)d_ws;
  unsigned int*   hbuf  = (unsigned int*)(ws + OFF_HBUF);
  unsigned short* wcat  = (unsigned short*)(ws + OFF_WCAT);
  unsigned short* whp   = (unsigned short*)(ws + OFF_WH);
  unsigned short* grw   = (unsigned short*)(ws + OFF_GR);
  unsigned short* giw   = (unsigned short*)(ws + OFF_GI);
  float* out = (float*)d_out;

  // zero tag region every launch (stale tags from prior replays must die)
  hipMemsetAsync(ws, 0, OFF_WCAT, stream);
  k_convert_weights<<<512, 256, 0, stream>>>(wri, wii, wni, wrh, wih, wnh, wcat, whp);
  k_gemm_x<<<6144, 256, 0, stream>>>(inputs, wcat, grw, giw, out, br, bi, bni);
  k_recurrent<<<128, 256, 0, stream>>>(whp, grw, giw, state, bnh, hbuf, out);
}

// Round 9
// 3357.418 us; speedup vs baseline: 1.0677x; 1.0677x over previous
//
#include <hip/hip_runtime.h>
#include <hip/hip_bf16.h>
#include <cstdio>

// QuantGRU: T=512, B=64, I=H=1024.
// k_gemm_x precomputes all x-projections (parallel GEMM, bf16 MFMA).
// k_recurrent: persistent 256-WG kernel. Per step, each WG cooperatively
// stages its group's 16x1024 h-slice into LDS ONCE (2 MB/step total vs 16 MB
// of per-wave duplicated loads in r6 -- the measured mall-bandwidth bound).
// Visibility protocol is r3-proven: WT (sc0 sc1) h stores -> vmcnt(0)+barrier
// -> WT sentinel -> sc0sc1 sentinel poll -> sc0sc1 coop load. Weights pinned
// in VGPRs via asm loads. Poll caps prevent timeouts.

typedef short bf16x8 __attribute__((ext_vector_type(8)));
typedef float f32x4 __attribute__((ext_vector_type(4)));
typedef int i32x4 __attribute__((ext_vector_type(4)));

#define NT 512
#define NB 64
#define NH 1024
#define NBH 65536   // NB*NH

// ws layout (bytes)
#define OFF_SENT  256UL                                    // 256 x 4B sentinels
#define OFF_HBUF  4096UL                                   // 2 x 64x1024 bf16 = 256KB
#define OFF_WCAT  (OFF_HBUF + 2UL * NB * NH * 2)           // 3072x1024 bf16 (Wri|Wii|Wni)
#define OFF_WH    (OFF_WCAT + 3UL * NH * NH * 2)           // 3 x 1024x1024 bf16 (Wrh,Wih,Wnh)
#define OFF_GR    (OFF_WH   + 3UL * NH * NH * 2)           // 32768x1024 bf16
#define OFF_GI    (OFF_GR   + (unsigned long)NT * NB * NH * 2)
#define WS_NEED   (OFF_GI   + (unsigned long)NT * NB * NH * 2)   // ~140.3 MB

__device__ __forceinline__ float clampf(float x) { return fminf(fmaxf(x, -1.f), 1.f); }

__device__ __forceinline__ unsigned short f2bf(float x) {
  __hip_bfloat16 h = __float2bfloat16(x);
  union { __hip_bfloat16 h; unsigned short u; } cv;
  cv.h = h;
  return cv.u;
}
__device__ __forceinline__ float bf2f(unsigned short u) {
  return __uint_as_float(((unsigned)u) << 16);
}
__device__ __forceinline__ float frcp(float x) { return __builtin_amdgcn_rcpf(x); }
__device__ __forceinline__ float fsigmoid(float x) { return frcp(1.f + __expf(-x)); }
__device__ __forceinline__ float ftanh(float z) { return 1.f - 2.f * frcp(1.f + __expf(2.f * z)); }

__device__ __forceinline__ i32x4 pack8(float4 v0, float4 v1) {
  i32x4 q;
  q[0] = (int)(f2bf(clampf(v0.x)) | ((unsigned)f2bf(clampf(v0.y)) << 16));
  q[1] = (int)(f2bf(clampf(v0.z)) | ((unsigned)f2bf(clampf(v0.w)) << 16));
  q[2] = (int)(f2bf(clampf(v1.x)) | ((unsigned)f2bf(clampf(v1.y)) << 16));
  q[3] = (int)(f2bf(clampf(v1.z)) | ((unsigned)f2bf(clampf(v1.w)) << 16));
  return q;
}

// 8x dwordx4 cached loads into asm-pinned regs (no remat possible).
__device__ __forceinline__ void load_frags8(const unsigned short* p, i32x4 a[8]) {
  asm volatile(
      "global_load_dwordx4 %0, %8, off\n\t"
      "global_load_dwordx4 %1, %8, off offset:64\n\t"
      "global_load_dwordx4 %2, %8, off offset:128\n\t"
      "global_load_dwordx4 %3, %8, off offset:192\n\t"
      "global_load_dwordx4 %4, %8, off offset:256\n\t"
      "global_load_dwordx4 %5, %8, off offset:320\n\t"
      "global_load_dwordx4 %6, %8, off offset:384\n\t"
      "global_load_dwordx4 %7, %8, off offset:448\n\t"
      "s_waitcnt vmcnt(0)"
      : "=&v"(a[0]), "=&v"(a[1]), "=&v"(a[2]), "=&v"(a[3]),
        "=&v"(a[4]), "=&v"(a[5]), "=&v"(a[6]), "=&v"(a[7])
      : "v"(p)
      : "memory");
}
// write-through store to the coherence point (r3/r6-proven)
__device__ __forceinline__ void store_bf16_wt(unsigned short* p, unsigned v) {
  asm volatile("global_store_short %0, %1, off sc0 sc1" :: "v"(p), "v"(v) : "memory");
}
__device__ __forceinline__ void store_flag_wt(unsigned int* p, unsigned v) {
  asm volatile("global_store_dword %0, %1, off sc0 sc1" :: "v"(p), "v"(v) : "memory");
}
// coherent read at the mall (r6-proven sc0 sc1 class)
__device__ __forceinline__ unsigned load_flag_mall(const unsigned int* p) {
  unsigned v;
  asm volatile("global_load_dword %0, %1, off sc0 sc1\n\ts_waitcnt vmcnt(0)"
               : "=v"(v) : "v"(p) : "memory");
  return v;
}

// ---------------- kernel 0: weights f32 -> bf16 ---------------------------
__global__ void k_convert_weights(const float* __restrict__ wri, const float* __restrict__ wii,
                                  const float* __restrict__ wni, const float* __restrict__ wrh,
                                  const float* __restrict__ wih, const float* __restrict__ wnh,
                                  unsigned short* __restrict__ wcat, unsigned short* __restrict__ wh) {
  const long total = 6L * 1024 * 1024;
  long stride = (long)gridDim.x * blockDim.x * 4;
  for (long i = ((long)blockIdx.x * blockDim.x + threadIdx.x) * 4; i < total; i += stride) {
    int m = (int)(i >> 20);              // which matrix
    long off = i & 1048575L;
    const float* srcs[6] = {wri, wii, wni, wrh, wih, wnh};
    float4 v = *(const float4*)(srcs[m] + off);
    ushort4 o;
    o.x = f2bf(v.x); o.y = f2bf(v.y); o.z = f2bf(v.z); o.w = f2bf(v.w);
    unsigned short* dst = (m < 3) ? (wcat + ((long)m << 20) + off)
                                  : (wh + ((long)(m - 3) << 20) + off);
    *(ushort4*)dst = o;
  }
}

// ---------------- kernel 1: input projections GEMM ------------------------
#define BK 64
__launch_bounds__(256)
__global__ void k_gemm_x(const float* __restrict__ A,              // X f32 [32768][1024]
                         const unsigned short* __restrict__ Bw,    // Wcat bf16 [3072][1024]
                         unsigned short* __restrict__ gr, unsigned short* __restrict__ gi,
                         float* __restrict__ gni,                  // = d_out plane [32768][1024]
                         const float* __restrict__ br, const float* __restrict__ bi,
                         const float* __restrict__ bni) {
  __shared__ unsigned short As[128 * BK];
  __shared__ unsigned short Bs[128 * BK];

  int bid = blockIdx.x;
  int bm = bid / 24, bn = bid % 24;
  int tid = threadIdx.x;
  int lane = tid & 63, w = tid >> 6;
  int wm = w >> 1, wn = w & 1;

  long arow0 = (long)bm * 128;
  long brow0 = (long)bn * 128;

  f32x4 acc[4][4] = {};

  for (int kt = 0; kt < 1024; kt += BK) {
    __syncthreads();
#pragma unroll
    for (int it = 0; it < 4; ++it) {
      int f = it * 2048 + tid * 8;
      int r = f >> 6, c = f & 63;
      const float* ap = A + (arow0 + r) * 1024 + kt + c;
      float4 v0 = *(const float4*)ap;
      float4 v1 = *(const float4*)(ap + 4);
      i32x4 p = pack8(v0, v1);
      *(i32x4*)(&As[f]) = p;
      *(int4*)(&Bs[f]) = *(const int4*)(Bw + (brow0 + r) * 1024 + kt + c);
    }
    __syncthreads();
#pragma unroll
    for (int ks = 0; ks < 2; ++ks) {
      bf16x8 a[4], b[4];
#pragma unroll
      for (int fm = 0; fm < 4; ++fm)
        a[fm] = *(const bf16x8*)(&As[(wm * 64 + fm * 16 + (lane & 15)) * BK + ks * 32 + (lane >> 4) * 8]);
#pragma unroll
      for (int fn = 0; fn < 4; ++fn)
        b[fn] = *(const bf16x8*)(&Bs[(wn * 64 + fn * 16 + (lane & 15)) * BK + ks * 32 + (lane >> 4) * 8]);
#pragma unroll
      for (int fm = 0; fm < 4; ++fm)
#pragma unroll
        for (int fn = 0; fn < 4; ++fn)
          acc[fm][fn] = __builtin_amdgcn_mfma_f32_16x16x32_bf16(a[fm], b[fn], acc[fm][fn], 0, 0, 0);
    }
  }

  int g = bn >> 3;  // 0:r 1:i 2:ni (uniform per block)
  const float* bias = (g == 0) ? br : (g == 1) ? bi : bni;
#pragma unroll
  for (int fm = 0; fm < 4; ++fm) {
    long m = arow0 + wm * 64 + fm * 16 + (lane >> 4) * 4;
#pragma unroll
    for (int fn = 0; fn < 4; ++fn) {
      long n = brow0 + wn * 64 + fn * 16 + (lane & 15);
      long colg = n & 1023;
      float bv = bias[colg];
#pragma unroll
      for (int r2 = 0; r2 < 4; ++r2) {
        float v = acc[fm][fn][r2] + bv;
        long idx = (m + r2) * 1024 + colg;
        if (g == 0)      gr[idx] = f2bf(v);
        else if (g == 1) gi[idx] = f2bf(v);
        else             gni[idx] = clampf(v);   // pre-clamped ni (includes bias)
      }
    }
  }
}

// ---------------- kernel 2: persistent recurrence (LDS-staged h) ----------
// 256 WGs x 256 threads. WG = (j = wg&63: hidden cols j*16..+16, mb = wg>>6:
// batch rows mb*16..+16). Per step: MFMA from LDS h-slice (XOR-swizzled),
// LDS reduce, pointwise, WT h store, vmcnt drain + barrier, WT sentinel,
// sentinel poll (256B/WG), cooperative 32KB slice load -> LDS, barrier.
__launch_bounds__(256, 1)
__global__ void k_recurrent(const unsigned short* __restrict__ wh,   // [3][1024][1024] bf16
                            const unsigned short* __restrict__ gr,
                            const unsigned short* __restrict__ gi,
                            const float* __restrict__ state,
                            const float* __restrict__ bias_nh,
                            unsigned short* __restrict__ hbuf,       // [2][64][1024] bf16
                            unsigned int* __restrict__ sent,         // [256]
                            float* __restrict__ out) {               // [512][64][1024] + [64][1024]
  __shared__ unsigned short h_lds[16 * 1024];   // flat, XOR-swizzled
  __shared__ float red[4][3][256];

  int tid = threadIdx.x;
  int lane = tid & 63, w = tid >> 6;
  int wg = blockIdx.x;
  int j = wg & 63;
  int mb = wg >> 6;

  // ---- pinned weight fragments (96 VGPRs, 3 gates x 8 k-frags) ----
  int frow = j * 16 + (lane & 15);
  int fk0 = w * 256 + ((lane >> 4) * 8);
  i32x4 wfi[3][8];
#pragma unroll
  for (int g = 0; g < 3; ++g)
    load_frags8(wh + ((long)g << 20) + (long)frow * 1024 + fk0, wfi[g]);

  // ---- per-thread pointwise cell ----
  int crow = tid >> 4, ccol = tid & 15;
  int colg = j * 16 + ccol;
  long cellofs = (long)(mb * 16 + crow) * 1024 + colg;
  float h_local = clampf(state[cellofs]);
  float bnh = bias_nh[colg];

  const long slice0 = (long)mb * 16 * 1024;   // bf16 elems

  // ---- init h_lds from clamp(state), interleaved chunks + swizzle ----
#pragma unroll
  for (int c = 0; c < 8; ++c) {
    int n = c * 256 + tid;                      // 16B chunk index (8 bf16)
    const float* sp = state + slice0 + (long)n * 8;
    float4 v0 = *(const float4*)sp;
    float4 v1 = *(const float4*)(sp + 4);
    int flat = n * 16;
    int srow = flat >> 11;
    int swz = flat ^ ((srow & 7) << 4);
    *(i32x4*)((char*)h_lds + swz) = pack8(v0, v1);
  }

  // frag read addressing (matches r6's global layout exactly, via swizzle)
  const int rowb = (lane & 15) * 2048;
  const int colb = w * 512 + ((lane >> 4) * 16);   // byte col base
  const int rsw = (lane & 7) << 4;

  // prefetch t=0 pointwise inputs
  float grv = bf2f(gr[cellofs]);
  float giv = bf2f(gi[cellofs]);
  float gniv = out[cellofs];

  __syncthreads();

#pragma unroll 1
  for (int t = 0; t < NT; ++t) {
    f32x4 acc[3] = {};
#pragma unroll
    for (int s = 0; s < 8; ++s) {
      bf16x8 a = *(const bf16x8*)((const char*)h_lds + rowb + ((colb + s * 64) ^ rsw));
#pragma unroll
      for (int g = 0; g < 3; ++g)
        acc[g] = __builtin_amdgcn_mfma_f32_16x16x32_bf16(
            a, __builtin_bit_cast(bf16x8, wfi[g][s]), acc[g], 0, 0, 0);
    }

    // stage partials: cell = row*16+col, row=(lane>>4)*4+r, col=lane&15
#pragma unroll
    for (int g = 0; g < 3; ++g)
#pragma unroll
      for (int r = 0; r < 4; ++r)
        red[w][g][((lane >> 4) * 4 + r) * 16 + (lane & 15)] = acc[g][r];
    __syncthreads();                                  // B1

    float pr = red[0][0][tid] + red[1][0][tid] + red[2][0][tid] + red[3][0][tid];
    float pi = red[0][1][tid] + red[1][1][tid] + red[2][1][tid] + red[3][1][tid];
    float pn = red[0][2][tid] + red[1][2][tid] + red[2][2][tid] + red[3][2][tid];

    float rg = fsigmoid(pr + grv);
    float ig = fsigmoid(pi + giv);
    float ng = ftanh(gniv + clampf(rg * (pn + bnh)));
    float sx = clampf(h_local) - ng;
    float hy = ng + clampf(ig * sx);

    long gofs = (long)t * NBH + cellofs;
    out[gofs] = hy;
    h_local = hy;

    unsigned tgt = (unsigned)(t + 1);
    long bank = (long)(tgt & 1) * NBH;
    store_bf16_wt(hbuf + bank + cellofs, (unsigned)f2bf(hy));

    if (t + 1 < NT) {           // prefetch next pointwise inputs (private)
      long g2 = (long)tgt * NBH + cellofs;
      grv = bf2f(gr[g2]); giv = bf2f(gi[g2]); gniv = out[g2];
    }

    asm volatile("s_waitcnt vmcnt(0)" ::: "memory");
    __syncthreads();                                  // B2: all WT h-stores acked

    if (t + 1 < NT) {
      if (tid == 0) store_flag_wt(&sent[wg], tgt);

      // per-lane sentinel poll: lane l waits for producer WG (mb<<6)|l
      unsigned it = 0;
      while (load_flag_mall(&sent[(mb << 6) + lane]) < tgt && it < 1024u) {
        ++it;
        __builtin_amdgcn_s_sleep(1);
      }

      // cooperative 32KB slice load (perfectly chunked) -> swizzled LDS
      i32x4 d[8];
      const unsigned short* base = hbuf + bank + slice0;
#pragma unroll
      for (int c = 0; c < 8; ++c) {
        const unsigned short* p = base + (long)(c * 256 + tid) * 8;
        asm volatile("global_load_dwordx4 %0, %1, off sc0 sc1"
                     : "=&v"(d[c]) : "v"(p) : "memory");
      }
      asm volatile("s_waitcnt vmcnt(0)" ::: "memory");
      __builtin_amdgcn_sched_barrier(0);
#pragma unroll
      for (int c = 0; c < 8; ++c) {
        int flat = (c * 256 + tid) * 16;
        int srow = flat >> 11;
        int swz = flat ^ ((srow & 7) << 4);
        *(i32x4*)((char*)h_lds + swz) = d[c];
      }
      __syncthreads();                                // B3: h_lds ready
    }
  }

  // last hidden state
  out[(long)NT * NBH + cellofs] = h_local;
}

// ---------------------------------------------------------------------------
extern "C" void kernel_launch(void* const* d_in, const int* in_sizes, int n_in,
                              void* d_out, int out_size, void* d_ws, size_t ws_size,
                              hipStream_t stream) {
  const float* inputs = (const float*)d_in[0];
  const float* state  = (const float*)d_in[1];
  const float* wri = (const float*)d_in[2];
  const float* wii = (const float*)d_in[3];
  const float* wni = (const float*)d_in[4];
  const float* wrh = (const float*)d_in[5];
  const float* wih = (const float*)d_in[6];
  const float* wnh = (const float*)d_in[7];
  const float* br  = (const float*)d_in[8];
  const float* bi  = (const float*)d_in[9];
  const float* bni = (const float*)d_in[10];
  const float* bnh = (const float*)d_in[11];

  if (ws_size < WS_NEED) {
    fprintf(stderr, "kernel_launch: ws too small (%zu < %lu)\n", ws_size, WS_NEED);
    return;
  }

  char* ws = (char*)d_ws;
  unsigned int*   sent  = (unsigned int*)(ws + OFF_SENT);
  unsigned short* hbuf  = (unsigned short*)(ws + OFF_HBUF);
  unsigned short* wcat  = (unsigned short*)(ws + OFF_WCAT);
  unsigned short* whp   = (unsigned short*)(ws + OFF_WH);
  unsigned short* grw   = (unsigned short*)(ws + OFF_GR);
  unsigned short* giw   = (unsigned short*)(ws + OFF_GI);
  float* out = (float*)d_out;

  // zero sentinels every launch (stale values from prior replays must die)
  hipMemsetAsync(ws, 0, 4096, stream);
  k_convert_weights<<<512, 256, 0, stream>>>(wri, wii, wni, wrh, wih, wnh, wcat, whp);
  k_gemm_x<<<6144, 256, 0, stream>>>(inputs, wcat, grw, giw, out, br, bi, bni);
  k_recurrent<<<256, 256, 0, stream>>>(whp, grw, giw, state, bnh, hbuf, sent, out);
}

// Round 10
// 1985.688 us; speedup vs baseline: 1.8053x; 1.6908x over previous
//
#include <hip/hip_runtime.h>
#include <hip/hip_bf16.h>
#include <cstdio>

// QuantGRU: T=512, B=64, I=H=1024.
// k_gemm_x precomputes all x-projections (parallel GEMM, bf16 MFMA).
// k_recurrent: persistent 256-WG kernel, 8 groups x 8 batch rows, 32 WGs per
// group each owning 32 hidden cols (x3 gates; 192 asm-pinned weight VGPRs).
// h exchange = r6-proven TAGGED WORDS (u32 = (bf16(h)<<16)|step, sc0 sc1 both
// sides, 1 mall RT, no flags/fences/drains) + r9-style cooperative staging
// into swizzled LDS (32KB/WG/step -> 8MB/step chip-wide, half of r6).
// Poll caps prevent timeouts.

typedef short bf16x8 __attribute__((ext_vector_type(8)));
typedef float f32x4 __attribute__((ext_vector_type(4)));
typedef int i32x4 __attribute__((ext_vector_type(4)));

#define NT 512
#define NB 64
#define NH 1024
#define NBH 65536   // NB*NH

// ws layout (bytes)
#define OFF_HBUF  4096UL                                   // 2 x 64x1024 u32 = 512KB (tagged)
#define OFF_WCAT  (OFF_HBUF + 2UL * NB * NH * 4)           // 3072x1024 bf16 (Wri|Wii|Wni)
#define OFF_WH    (OFF_WCAT + 3UL * NH * NH * 2)           // 3 x 1024x1024 bf16 (Wrh,Wih,Wnh)
#define OFF_GR    (OFF_WH   + 3UL * NH * NH * 2)           // 32768x1024 bf16
#define OFF_GI    (OFF_GR   + (unsigned long)NT * NB * NH * 2)
#define WS_NEED   (OFF_GI   + (unsigned long)NT * NB * NH * 2)   // ~140.6 MB

__device__ __forceinline__ float clampf(float x) { return fminf(fmaxf(x, -1.f), 1.f); }

__device__ __forceinline__ unsigned short f2bf(float x) {
  __hip_bfloat16 h = __float2bfloat16(x);
  union { __hip_bfloat16 h; unsigned short u; } cv;
  cv.h = h;
  return cv.u;
}
__device__ __forceinline__ float bf2f(unsigned short u) {
  return __uint_as_float(((unsigned)u) << 16);
}
__device__ __forceinline__ float frcp(float x) { return __builtin_amdgcn_rcpf(x); }
__device__ __forceinline__ float fsigmoid(float x) { return frcp(1.f + __expf(-x)); }
__device__ __forceinline__ float ftanh(float z) { return 1.f - 2.f * frcp(1.f + __expf(2.f * z)); }

__device__ __forceinline__ i32x4 pack8(float4 v0, float4 v1) {
  i32x4 q;
  q[0] = (int)(f2bf(clampf(v0.x)) | ((unsigned)f2bf(clampf(v0.y)) << 16));
  q[1] = (int)(f2bf(clampf(v0.z)) | ((unsigned)f2bf(clampf(v0.w)) << 16));
  q[2] = (int)(f2bf(clampf(v1.x)) | ((unsigned)f2bf(clampf(v1.y)) << 16));
  q[3] = (int)(f2bf(clampf(v1.z)) | ((unsigned)f2bf(clampf(v1.w)) << 16));
  return q;
}

// 8x dwordx4 cached loads into asm-pinned regs (no remat possible).
__device__ __forceinline__ void load_frags8(const unsigned short* p, i32x4 a[8]) {
  asm volatile(
      "global_load_dwordx4 %0, %8, off\n\t"
      "global_load_dwordx4 %1, %8, off offset:64\n\t"
      "global_load_dwordx4 %2, %8, off offset:128\n\t"
      "global_load_dwordx4 %3, %8, off offset:192\n\t"
      "global_load_dwordx4 %4, %8, off offset:256\n\t"
      "global_load_dwordx4 %5, %8, off offset:320\n\t"
      "global_load_dwordx4 %6, %8, off offset:384\n\t"
      "global_load_dwordx4 %7, %8, off offset:448\n\t"
      "s_waitcnt vmcnt(0)"
      : "=&v"(a[0]), "=&v"(a[1]), "=&v"(a[2]), "=&v"(a[3]),
        "=&v"(a[4]), "=&v"(a[5]), "=&v"(a[6]), "=&v"(a[7])
      : "v"(p)
      : "memory");
}
// fire-and-forget write-through store (r6-proven visibility path)
__device__ __forceinline__ void store_u32_wt(unsigned int* p, unsigned v) {
  asm volatile("global_store_dword %0, %1, off sc0 sc1" :: "v"(p), "v"(v) : "memory");
}

// ---------------- kernel 0: weights f32 -> bf16 ---------------------------
__global__ void k_convert_weights(const float* __restrict__ wri, const float* __restrict__ wii,
                                  const float* __restrict__ wni, const float* __restrict__ wrh,
                                  const float* __restrict__ wih, const float* __restrict__ wnh,
                                  unsigned short* __restrict__ wcat, unsigned short* __restrict__ wh) {
  const long total = 6L * 1024 * 1024;
  long stride = (long)gridDim.x * blockDim.x * 4;
  for (long i = ((long)blockIdx.x * blockDim.x + threadIdx.x) * 4; i < total; i += stride) {
    int m = (int)(i >> 20);              // which matrix
    long off = i & 1048575L;
    const float* srcs[6] = {wri, wii, wni, wrh, wih, wnh};
    float4 v = *(const float4*)(srcs[m] + off);
    ushort4 o;
    o.x = f2bf(v.x); o.y = f2bf(v.y); o.z = f2bf(v.z); o.w = f2bf(v.w);
    unsigned short* dst = (m < 3) ? (wcat + ((long)m << 20) + off)
                                  : (wh + ((long)(m - 3) << 20) + off);
    *(ushort4*)dst = o;
  }
}

// ---------------- kernel 1: input projections GEMM ------------------------
#define BK 64
__launch_bounds__(256)
__global__ void k_gemm_x(const float* __restrict__ A,              // X f32 [32768][1024]
                         const unsigned short* __restrict__ Bw,    // Wcat bf16 [3072][1024]
                         unsigned short* __restrict__ gr, unsigned short* __restrict__ gi,
                         float* __restrict__ gni,                  // = d_out plane [32768][1024]
                         const float* __restrict__ br, const float* __restrict__ bi,
                         const float* __restrict__ bni) {
  __shared__ unsigned short As[128 * BK];
  __shared__ unsigned short Bs[128 * BK];

  int bid = blockIdx.x;
  int bm = bid / 24, bn = bid % 24;
  int tid = threadIdx.x;
  int lane = tid & 63, w = tid >> 6;
  int wm = w >> 1, wn = w & 1;

  long arow0 = (long)bm * 128;
  long brow0 = (long)bn * 128;

  f32x4 acc[4][4] = {};

  for (int kt = 0; kt < 1024; kt += BK) {
    __syncthreads();
#pragma unroll
    for (int it = 0; it < 4; ++it) {
      int f = it * 2048 + tid * 8;
      int r = f >> 6, c = f & 63;
      const float* ap = A + (arow0 + r) * 1024 + kt + c;
      float4 v0 = *(const float4*)ap;
      float4 v1 = *(const float4*)(ap + 4);
      i32x4 p = pack8(v0, v1);
      *(i32x4*)(&As[f]) = p;
      *(int4*)(&Bs[f]) = *(const int4*)(Bw + (brow0 + r) * 1024 + kt + c);
    }
    __syncthreads();
#pragma unroll
    for (int ks = 0; ks < 2; ++ks) {
      bf16x8 a[4], b[4];
#pragma unroll
      for (int fm = 0; fm < 4; ++fm)
        a[fm] = *(const bf16x8*)(&As[(wm * 64 + fm * 16 + (lane & 15)) * BK + ks * 32 + (lane >> 4) * 8]);
#pragma unroll
      for (int fn = 0; fn < 4; ++fn)
        b[fn] = *(const bf16x8*)(&Bs[(wn * 64 + fn * 16 + (lane & 15)) * BK + ks * 32 + (lane >> 4) * 8]);
#pragma unroll
      for (int fm = 0; fm < 4; ++fm)
#pragma unroll
        for (int fn = 0; fn < 4; ++fn)
          acc[fm][fn] = __builtin_amdgcn_mfma_f32_16x16x32_bf16(a[fm], b[fn], acc[fm][fn], 0, 0, 0);
    }
  }

  int g = bn >> 3;  // 0:r 1:i 2:ni (uniform per block)
  const float* bias = (g == 0) ? br : (g == 1) ? bi : bni;
#pragma unroll
  for (int fm = 0; fm < 4; ++fm) {
    long m = arow0 + wm * 64 + fm * 16 + (lane >> 4) * 4;
#pragma unroll
    for (int fn = 0; fn < 4; ++fn) {
      long n = brow0 + wn * 64 + fn * 16 + (lane & 15);
      long colg = n & 1023;
      float bv = bias[colg];
#pragma unroll
      for (int r2 = 0; r2 < 4; ++r2) {
        float v = acc[fm][fn][r2] + bv;
        long idx = (m + r2) * 1024 + colg;
        if (g == 0)      gr[idx] = f2bf(v);
        else if (g == 1) gi[idx] = f2bf(v);
        else             gni[idx] = clampf(v);   // pre-clamped ni (includes bias)
      }
    }
  }
}

// ---------------- kernel 2: persistent recurrence -------------------------
// 256 WGs x 256 threads. grp = wg>>5 (8 groups x 8 batch rows), slot = wg&31
// (32 hidden cols x 3 gates). Per step: MFMA from swizzled LDS h (M=8 via
// row duplication), LDS reduce, pointwise (1 cell/thread, 8x32), tagged WT
// h store (fire&forget), cooperative tagged poll of the 8x1024 group slice
// (8 x 16B chunks/thread), v_perm unpack -> swizzled ds_write, barrier.
__launch_bounds__(256, 1)
__global__ void k_recurrent(const unsigned short* __restrict__ wh,   // [3][1024][1024] bf16
                            const unsigned short* __restrict__ gr,
                            const unsigned short* __restrict__ gi,
                            const float* __restrict__ state,
                            const float* __restrict__ bias_nh,
                            unsigned int* __restrict__ hbuf,         // [2][64][1024] u32 tagged
                            float* __restrict__ out) {               // [512][64][1024] + [64][1024]
  __shared__ unsigned short h_lds[8 * 1024];       // 16KB, XOR-swizzled
  __shared__ float red[4][3][2][8][16];            // 12KB

  int tid = threadIdx.x;
  int lane = tid & 63, w = tid >> 6;
  int wg = blockIdx.x;
  int grp = wg >> 5;      // batch rows grp*8..+8
  int slot = wg & 31;     // hidden cols slot*32..+32

  // ---- pinned weights: 3 gates x 2 n-tiles x 8 k-frags = 192 VGPRs ----
  int klane = (lane >> 4) * 8;
  int k0 = w * 256;
  i32x4 wfi[3][2][8];
#pragma unroll
  for (int g2 = 0; g2 < 3; ++g2)
#pragma unroll
    for (int n2 = 0; n2 < 2; ++n2) {
      int col = slot * 32 + n2 * 16 + (lane & 15);
      load_frags8(wh + ((long)g2 << 20) + (long)col * 1024 + k0 + klane, wfi[g2][n2]);
    }

  // ---- per-thread pointwise cell: row=tid>>5 (0..7), col=tid&31 ----
  int row = tid >> 5, col = tid & 31;
  long cellofs = (long)(grp * 8 + row) * 1024 + slot * 32 + col;
  float h_local = clampf(state[cellofs]);
  float bnh = bias_nh[slot * 32 + col];

  // ---- init h_lds from clamp(state): 4 x 16B chunks/thread, swizzled ----
#pragma unroll
  for (int c = 0; c < 4; ++c) {
    int m = c * 256 + tid;                    // 16B chunk id (0..1023)
    const float* sp = state + (long)grp * 8192 + (long)m * 8;
    float4 v0 = *(const float4*)sp;
    float4 v1 = *(const float4*)(sp + 4);
    int flat = m * 16;
    int r8 = m >> 7;                          // row 0..7
    *(i32x4*)((char*)h_lds + (flat ^ (r8 << 4))) = pack8(v0, v1);
  }

  // ---- LDS fragment read addressing (M=8: rows duplicated, row = lane&7) ----
  const int rowb = (lane & 7) * 2048;
  const int colb = w * 512 + ((lane >> 4) * 16);  // byte col base
  const int rsw = (lane & 7) << 4;

  // prefetch t=0 pointwise inputs
  float grv = bf2f(gr[cellofs]);
  float giv = bf2f(gi[cellofs]);
  float gniv = out[cellofs];

  __syncthreads();

#pragma unroll 1
  for (int t = 0; t < NT; ++t) {
    f32x4 acc[3][2] = {};
#pragma unroll
    for (int s = 0; s < 8; ++s) {
      bf16x8 a = *(const bf16x8*)((const char*)h_lds + rowb + ((colb + s * 64) ^ rsw));
#pragma unroll
      for (int g2 = 0; g2 < 3; ++g2)
#pragma unroll
        for (int n2 = 0; n2 < 2; ++n2)
          acc[g2][n2] = __builtin_amdgcn_mfma_f32_16x16x32_bf16(
              a, __builtin_bit_cast(bf16x8, wfi[g2][n2][s]), acc[g2][n2], 0, 0, 0);
    }

    // stage valid C rows (rows 0..7 live in lanes 0..31)
    int rq = lane >> 4;
    if (rq < 2) {
#pragma unroll
      for (int g2 = 0; g2 < 3; ++g2)
#pragma unroll
        for (int n2 = 0; n2 < 2; ++n2)
#pragma unroll
          for (int r = 0; r < 4; ++r)
            red[w][g2][n2][rq * 4 + r][lane & 15] = acc[g2][n2][r];
    }
    __syncthreads();                                  // B1

    int n2c = col >> 4, cc = col & 15;
    float pr = red[0][0][n2c][row][cc] + red[1][0][n2c][row][cc]
             + red[2][0][n2c][row][cc] + red[3][0][n2c][row][cc];
    float pi = red[0][1][n2c][row][cc] + red[1][1][n2c][row][cc]
             + red[2][1][n2c][row][cc] + red[3][1][n2c][row][cc];
    float pn = red[0][2][n2c][row][cc] + red[1][2][n2c][row][cc]
             + red[2][2][n2c][row][cc] + red[3][2][n2c][row][cc];

    float rg = fsigmoid(pr + grv);
    float ig = fsigmoid(pi + giv);
    float ng = ftanh(gniv + clampf(rg * (pn + bnh)));
    float sx = clampf(h_local) - ng;
    float hy = ng + clampf(ig * sx);

    out[(long)t * NBH + cellofs] = hy;
    h_local = hy;

    unsigned tgt = (unsigned)(t + 1);
    long bank = (long)(tgt & 1) * NBH;
    // publish tagged h(t+1): fire-and-forget, data+tag in one word
    store_u32_wt(hbuf + bank + cellofs, ((unsigned)f2bf(hy) << 16) | tgt);

    if (t + 1 < NT) {
      // prefetch next step's pointwise inputs (private, cached)
      long g2ofs = (long)tgt * NBH + cellofs;
      grv = bf2f(gr[g2ofs]); giv = bf2f(gi[g2ofs]); gniv = out[g2ofs];

      // cooperative tagged poll: 8 x 16B chunks/thread of the group slice
      const unsigned int* base = hbuf + bank + (long)grp * 8192;
      i32x4 d[8];
      for (unsigned it = 0;; ++it) {
#pragma unroll
        for (int c = 0; c < 8; ++c) {
          const unsigned int* p = base + (long)(c * 256 + tid) * 4;
          asm volatile("global_load_dwordx4 %0, %1, off sc0 sc1"
                       : "=&v"(d[c]) : "v"(p) : "memory");
        }
        asm volatile("s_waitcnt vmcnt(0)" ::: "memory");
        unsigned mn = 0xFFFFFFFFu;
#pragma unroll
        for (int c = 0; c < 8; ++c)
#pragma unroll
          for (int e = 0; e < 4; ++e)
            mn = min(mn, ((unsigned)d[c][e]) & 0xFFFFu);
        if (__all((int)(mn >= tgt)) || it > 4096u) break;
        __builtin_amdgcn_s_sleep(2);
      }
      // unpack hi16 -> bf16 pairs, swizzled 8B LDS writes
#pragma unroll
      for (int c = 0; c < 8; ++c) {
        int n = c * 256 + tid;                // 8B chunk id (0..2047)
        int flat = n * 8;
        int r8 = n >> 8;                      // row 0..7
        int swz = flat ^ (r8 << 4);
        int2 v;
        v.x = (int)__builtin_amdgcn_perm((unsigned)d[c][1], (unsigned)d[c][0], 0x07060302u);
        v.y = (int)__builtin_amdgcn_perm((unsigned)d[c][3], (unsigned)d[c][2], 0x07060302u);
        *(int2*)((char*)h_lds + swz) = v;
      }
      __syncthreads();                                // B2: h_lds(t+1) ready
    }
  }

  // last hidden state
  out[(long)NT * NBH + cellofs] = h_local;
}

// ---------------------------------------------------------------------------
extern "C" void kernel_launch(void* const* d_in, const int* in_sizes, int n_in,
                              void* d_out, int out_size, void* d_ws, size_t ws_size,
                              hipStream_t stream) {
  const float* inputs = (const float*)d_in[0];
  const float* state  = (const float*)d_in[1];
  const float* wri = (const float*)d_in[2];
  const float* wii = (const float*)d_in[3];
  const float* wni = (const float*)d_in[4];
  const float* wrh = (const float*)d_in[5];
  const float* wih = (const float*)d_in[6];
  const float* wnh = (const float*)d_in[7];
  const float* br  = (const float*)d_in[8];
  const float* bi  = (const float*)d_in[9];
  const float* bni = (const float*)d_in[10];
  const float* bnh = (const float*)d_in[11];

  if (ws_size < WS_NEED) {
    fprintf(stderr, "kernel_launch: ws too small (%zu < %lu)\n", ws_size, WS_NEED);
    return;
  }

  char* ws = (char*)d_ws;
  unsigned int*   hbuf  = (unsigned int*)(ws + OFF_HBUF);
  unsigned short* wcat  = (unsigned short*)(ws + OFF_WCAT);
  unsigned short* whp   = (unsigned short*)(ws + OFF_WH);
  unsigned short* grw   = (unsigned short*)(ws + OFF_GR);
  unsigned short* giw   = (unsigned short*)(ws + OFF_GI);
  float* out = (float*)d_out;

  // zero tag region every launch (stale tags from prior replays must die)
  hipMemsetAsync(ws, 0, OFF_WCAT, stream);
  k_convert_weights<<<512, 256, 0, stream>>>(wri, wii, wni, wrh, wih, wnh, wcat, whp);
  k_gemm_x<<<6144, 256, 0, stream>>>(inputs, wcat, grw, giw, out, br, bi, bni);
  k_recurrent<<<256, 256, 0, stream>>>(whp, grw, giw, state, bnh, hbuf, out);
}